// Round 2
// baseline (132.205 us; speedup 1.0000x reference)
//
#include <hip/hip_runtime.h>

// Problem constants
#define NIMG 4
#define CCH  3
#define KCH  21
#define HIN  128
#define WIN  128
#define OH   64
#define OW   64
#define PPX  (OH*OW)          // 4096 pixels after 0.5x downsample
#define NPIX (NIMG*PPX)       // 16384 = 2^14

// feature prescale: sqrt(2)*sqrt(0.5*log2(e)) so that
//   exp(-0.5*d2) == exp2( v_i . v_j - h_i - h_j ),  h = 0.5*|v|^2
#define PRE2 1.20112241f

#define SEGW  24              // halfs per pixel: 21 seg + 3 zero (48B)
#define FEATW 8               // halfs per pixel: 5 feat + 3 zero (16B)

#define BLOCK  256
#define JCHUNK 256            // j-pixels staged per block
#define IBLK   64             // i-pixels per block (16 per wave)

#define NBLK_IMG 544          // sum_g 4*(16-g)
#define NBLK_TOT (NBLK_IMG*NIMG)   // 2176

#define NSLOT  64             // partial-sum cachelines (atomic spreading)

typedef _Float16 half_t;
typedef half_t half8  __attribute__((ext_vector_type(8)));
typedef float  f32x4v __attribute__((ext_vector_type(4)));

// ws layout (bytes): segH | featH | sqF | slots | ticket
#define FEATH_OFF ((size_t)NPIX*SEGW*2)
#define SQF_OFF   (FEATH_OFF + (size_t)NPIX*FEATW*2)
#define SLOT_OFF  (SQF_OFF + (size_t)NPIX*4)

// ---------------------------------------------------------------------------
// Prep: pixel-fast indexing (g = q*NPIX + pl) so every global read is a
// 64-lane contiguous segment and featH/sqF writes coalesce.
// q<24 -> seg channel (2x2 avg pool * nearest ROI) as f16;
// q==24 -> 5 prescaled features as f16 (padded half8) + fp32 h = 0.5|v|^2
// from the f16-ROUNDED v so E_ii == 0 exactly.
// q==25 -> zero the partial-sum slots + ticket counter.
// ---------------------------------------------------------------------------
__global__ __launch_bounds__(BLOCK) void crf_prep(const float* __restrict__ img,
                                                  const float* __restrict__ seg,
                                                  const float* __restrict__ roi,
                                                  half_t* __restrict__ segH,
                                                  half_t* __restrict__ featH,
                                                  float* __restrict__ sqF,
                                                  float* __restrict__ slots) {
    int g  = blockIdx.x * BLOCK + threadIdx.x;    // [0, 26*NPIX)
    int q  = g >> 14;                             // slow: record element
    int pl = g & (NPIX - 1);                      // fast: linear pixel
    int n  = pl >> 12;
    int p  = pl & (PPX - 1);
    int y = p >> 6, x = p & 63;
    int y2 = 2 * y, x2 = 2 * x;

    if (q < SEGW) {
        float v = 0.0f;
        if (q < KCH) {
            const float* s0 = seg + (((size_t)n * KCH + q) * HIN + y2) * WIN + x2;
            float r = roi[((size_t)n * HIN + y2) * WIN + x2];
            v = 0.25f * (s0[0] + s0[1] + s0[WIN] + s0[WIN + 1]) * r;
        }
        segH[(size_t)pl * SEGW + q] = (half_t)v;
    } else if (q == 24) {
        float fx = (float)x * (PRE2 / 50.0f);
        float fy = (float)y * (PRE2 / 50.0f);
        const size_t ib = (((size_t)n * CCH) * HIN + y2) * WIN + x2;
        float fr = img[ib]                         * (PRE2 / 0.15f);
        float fg = img[ib + (size_t)HIN * WIN]     * (PRE2 / 0.15f);
        float fb = img[ib + 2 * (size_t)HIN * WIN] * (PRE2 / 0.15f);
        half_t h0 = (half_t)fx, h1 = (half_t)fy, h2 = (half_t)fr,
               h3 = (half_t)fg, h4 = (half_t)fb;
        half8 fh = {h0, h1, h2, h3, h4, (half_t)0, (half_t)0, (half_t)0};
        *(half8*)(featH + (size_t)pl * FEATW) = fh;
        float a0 = (float)h0, a1 = (float)h1, a2 = (float)h2,
              a3 = (float)h3, a4 = (float)h4;
        sqF[pl] = 0.5f * (a0 * a0 + a1 * a1 + a2 * a2 + a3 * a3 + a4 * a4);
    } else if (q == 25) {
        if (pl < NSLOT) slots[pl * 16] = 0.0f;    // one slot per cacheline
        if (pl == NSLOT) ((unsigned*)slots)[NSLOT * 16] = 0u;  // ticket
    }
}

// ---------------------------------------------------------------------------
// Main: per 16x16 pair tile, two mfma_f32_16x16x32_f16:
//   E  = mfma(afeat, bfeat, c4)   with c4[r] = -h_i(row r) - h_j(col)
//   Gs = mfma(aseg,  bseg,  0)
//   term = exp2(E) * Gs     (diag blocks add {+1,0,-inf} in log2 space)
//
// Geometry: 64-row i-blocks x 256-col j-chunks, upper triangle -> 544
// blocks/image, 2176 total = 8.5 blocks/CU. R1 POST-MORTEM: this kernel is
// LATENCY-bound (VALUBusy ~12%, issue floor ~7us) -- a 128-row/1088-block
// variant regressed 3x because residency fell to 4.25 blocks/CU. Full
// 8-blocks/CU residency (VGPR=32-40, LDS=17.9KB both allow it; hence
// launch_bounds(256,8)) is the single most important property here.
//
// Partials -> 64 spread cachelines; the LAST block (device ticket) reduces
// the slots with agent-scope atomic loads (safe across non-coherent per-XCD
// L2s) and writes the scalar output -- no separate final dispatch.
// ---------------------------------------------------------------------------
__global__ __launch_bounds__(BLOCK, 8) void crf_main(const half_t* __restrict__ segH,
                                                     const half_t* __restrict__ featH,
                                                     const float* __restrict__ sqF,
                                                     float* __restrict__ slots,
                                                     float* __restrict__ out) {
    const int bx = blockIdx.x;
    const int n  = blockIdx.y;

    // triangular decode: g = I>>2 group; 4 I's per group, 16-g J's each
    int g = 0;
#pragma unroll
    for (int t = 1; t < 16; ++t) {
        int off = 64 * t - 2 * t * (t - 1);
        if (bx >= off) g = t;
    }
    int rem = bx - (64 * g - 2 * g * (g - 1));
    int c   = 16 - g;
    int iq  = (rem >= c) + (rem >= 2 * c) + (rem >= 3 * c);
    int I   = 4 * g + iq;
    int J   = g + (rem - iq * c);
    const bool diag = (J == (I >> 2));

    const half_t* segN  = segH  + (size_t)n * PPX * SEGW;
    const half_t* featN = featH + (size_t)n * PPX * FEATW;
    const float*  sqN   = sqF   + (size_t)n * PPX;

    __shared__ alignas(16) half_t segJ[JCHUNK * SEGW];    // 12 KB
    __shared__ alignas(16) half_t featJ[JCHUNK * FEATW];  // 4 KB
    __shared__ alignas(16) half_t zrow[8];                // 16 B of zeros
    __shared__ float hJ[JCHUNK];                          // 1 KB
    __shared__ float wsum[BLOCK / 64];
    __shared__ int lastBlk;

    const int tid  = threadIdx.x;
    const int lane = tid & 63, wv = tid >> 6;
    const int m = lane & 15, quad = lane >> 4;
    const int i0 = I * IBLK + wv * 16;
    const int j0 = J * JCHUNK;
    const int kq = (quad < 2) ? quad : 2;   // seg k-slice (quad3 -> zero row)

    half8 hz = {};

    // A-frags from global (reused over all 16 j-tiles)
    half8 aseg  = *(const half8*)(segN  + (size_t)(i0 + m) * SEGW + kq * 8);
    half8 afeat = *(const half8*)(featN + (size_t)(i0 + m) * FEATW);
    f32x4v hi   = *(const f32x4v*)(sqN + i0 + quad * 4);  // rows quad*4..+3
    if (quad == 3) aseg  = hz;
    if (quad != 0) afeat = hz;
    f32x4v nh = -hi;

    // stage j-chunk (flat coalesced 16B copies) + zero row
    {
        const f32x4v* gsrc = (const f32x4v*)(segN + (size_t)j0 * SEGW);
        f32x4v* ldst = (f32x4v*)segJ;
#pragma unroll
        for (int v = 0; v < 3; ++v) ldst[tid + v * BLOCK] = gsrc[tid + v * BLOCK];
        ((f32x4v*)featJ)[tid] = ((const f32x4v*)(featN + (size_t)j0 * FEATW))[tid];
        hJ[tid] = sqN[j0 + tid];
        if (tid < 8) zrow[tid] = (half_t)0;
    }
    __syncthreads();

    // per-lane B pointers: stride over j-tiles, or pinned to the zero row
    const half_t* bsp; int bstep;
    if (quad == 3) { bsp = zrow;                       bstep = 0; }
    else           { bsp = segJ + m * SEGW + quad * 8; bstep = 16 * SEGW; }
    const half_t* bfp; int fstep;
    if (quad == 0) { bfp = featJ + m * FEATW;          fstep = 16 * FEATW; }
    else           { bfp = zrow;                       fstep = 0; }

    float racc = 0.0f;
    const f32x4v zero4 = {0.0f, 0.0f, 0.0f, 0.0f};

#pragma unroll 4
    for (int jt = 0; jt < JCHUNK / 16; ++jt) {
        half8 bseg = *(const half8*)bsp;  bsp += bstep;
        half8 bft  = *(const half8*)bfp;  bfp += fstep;
        float hc = hJ[jt * 16 + m];

        f32x4v c4 = {nh[0] - hc, nh[1] - hc, nh[2] - hc, nh[3] - hc};
        f32x4v E  = __builtin_amdgcn_mfma_f32_16x16x32_f16(afeat, bft, c4, 0, 0, 0);
        f32x4v Gs = __builtin_amdgcn_mfma_f32_16x16x32_f16(aseg, bseg, zero4, 0, 0, 0);

        if (!diag) {
#pragma unroll
            for (int r = 0; r < 4; ++r)
                racc = fmaf(__builtin_amdgcn_exp2f(E[r]), Gs[r], racc);
        } else {
            const int jg = j0 + jt * 16 + m;
#pragma unroll
            for (int r = 0; r < 4; ++r) {
                int ig = i0 + quad * 4 + r;
                float sel = (jg > ig) ? 1.0f : ((jg == ig) ? 0.0f : -100000.0f);
                racc = fmaf(__builtin_amdgcn_exp2f(E[r] + sel), Gs[r], racc);
            }
        }
    }

    // reduce: thread -> wave -> block -> spread atomic slot
#pragma unroll
    for (int off = 32; off > 0; off >>= 1) racc += __shfl_down(racc, off);
    if (lane == 0) wsum[wv] = racc;
    __syncthreads();

    unsigned* ticket = (unsigned*)&slots[NSLOT * 16];
    if (tid == 0) {
        float s = wsum[0] + wsum[1] + wsum[2] + wsum[3];
        if (!diag) s *= 2.0f;              // strictly-upper counts (i,j)+(j,i)
        int slot = (bx + NBLK_IMG * n) & (NSLOT - 1);
        atomicAdd(&slots[slot * 16], s);
        __threadfence();
        unsigned t = __hip_atomic_fetch_add(ticket, 1u, __ATOMIC_ACQ_REL,
                                            __HIP_MEMORY_SCOPE_AGENT);
        lastBlk = (t == NBLK_TOT - 1);
    }
    __syncthreads();

    // last block: sum the 64 slots (agent-scope loads) and write the output
    if (lastBlk && tid < 64) {
        float v = __hip_atomic_load(&slots[tid * 16], __ATOMIC_ACQUIRE,
                                    __HIP_MEMORY_SCOPE_AGENT);
#pragma unroll
        for (int off = 32; off > 0; off >>= 1) v += __shfl_down(v, off);
        if (tid == 0) out[0] = v * (-5.0e-10f);   // WEIGHT * (-sum/NIMG)
    }
}

extern "C" void kernel_launch(void* const* d_in, const int* in_sizes, int n_in,
                              void* d_out, int out_size, void* d_ws, size_t ws_size,
                              hipStream_t stream) {
    const float* img = (const float*)d_in[0];
    const float* seg = (const float*)d_in[1];
    const float* roi = (const float*)d_in[2];
    float* out = (float*)d_out;

    char* wsb = (char*)d_ws;                    // ~1.07 MB of ws used
    half_t* segH  = (half_t*)(wsb);
    half_t* featH = (half_t*)(wsb + FEATH_OFF);
    float*  sqF   = (float*)(wsb + SQF_OFF);
    float*  slots = (float*)(wsb + SLOT_OFF);

    crf_prep<<<(NPIX * 26) / BLOCK, BLOCK, 0, stream>>>(img, seg, roi,
                                                        segH, featH, sqF, slots);

    dim3 grid(NBLK_IMG, NIMG);                  // 544 x 4 = 2176 blocks
    crf_main<<<grid, BLOCK, 0, stream>>>(segH, featH, sqF, slots, out);
}

// Round 3
// 75.724 us; speedup vs baseline: 1.7459x; 1.7459x over previous
//
#include <hip/hip_runtime.h>

// Problem constants
#define NIMG 4
#define CCH  3
#define KCH  21
#define HIN  128
#define WIN  128
#define OH   64
#define OW   64
#define PPX  (OH*OW)          // 4096 pixels after 0.5x downsample
#define NPIX (NIMG*PPX)       // 16384 = 2^14

// feature prescale: sqrt(2)*sqrt(0.5*log2(e)) so that
//   exp(-0.5*d2) == exp2( v_i . v_j - h_i - h_j ),  h = 0.5*|v|^2
#define PRE2 1.20112241f

#define SEGW  24              // halfs per pixel: 21 seg + 3 zero (48B)
#define FEATW 8               // halfs per pixel: 5 feat + 3 zero (16B)

#define BLOCK  256
#define JCHUNK 256            // j-pixels staged per block
#define IBLK   64             // i-pixels per block (16 per wave)

#define NSLOT  64             // partial-sum cachelines (atomic spreading)

typedef _Float16 half_t;
typedef half_t half8  __attribute__((ext_vector_type(8)));
typedef float  f32x4v __attribute__((ext_vector_type(4)));

// ws layout (bytes): segH | featH | sqF | slots
#define FEATH_OFF ((size_t)NPIX*SEGW*2)
#define SQF_OFF   (FEATH_OFF + (size_t)NPIX*FEATW*2)
#define SLOT_OFF  (SQF_OFF + (size_t)NPIX*4)

// ---------------------------------------------------------------------------
// Prep: pixel-fast indexing (g = q*NPIX + pl) so every global read is a
// 64-lane contiguous segment and featH/sqF writes coalesce.
// q<24 -> seg channel (2x2 avg pool * nearest ROI) as f16;
// q==24 -> 5 prescaled features as f16 (padded half8) + fp32 h = 0.5|v|^2
// from the f16-ROUNDED v so E_ii == 0 exactly.
// q==25, pl<64 -> zero the partial-sum slots.  Grid: q<26 (1664 blocks).
// ---------------------------------------------------------------------------
__global__ __launch_bounds__(BLOCK) void crf_prep(const float* __restrict__ img,
                                                  const float* __restrict__ seg,
                                                  const float* __restrict__ roi,
                                                  half_t* __restrict__ segH,
                                                  half_t* __restrict__ featH,
                                                  float* __restrict__ sqF,
                                                  float* __restrict__ slots) {
    int g  = blockIdx.x * BLOCK + threadIdx.x;    // [0, 26*NPIX)
    int q  = g >> 14;                             // slow: record element
    int pl = g & (NPIX - 1);                      // fast: linear pixel
    int n  = pl >> 12;
    int p  = pl & (PPX - 1);
    int y = p >> 6, x = p & 63;
    int y2 = 2 * y, x2 = 2 * x;

    if (q < SEGW) {
        float v = 0.0f;
        if (q < KCH) {
            const float* s0 = seg + (((size_t)n * KCH + q) * HIN + y2) * WIN + x2;
            float r = roi[((size_t)n * HIN + y2) * WIN + x2];
            v = 0.25f * (s0[0] + s0[1] + s0[WIN] + s0[WIN + 1]) * r;
        }
        segH[(size_t)pl * SEGW + q] = (half_t)v;
    } else if (q == 24) {
        float fx = (float)x * (PRE2 / 50.0f);
        float fy = (float)y * (PRE2 / 50.0f);
        const size_t ib = (((size_t)n * CCH) * HIN + y2) * WIN + x2;
        float fr = img[ib]                         * (PRE2 / 0.15f);
        float fg = img[ib + (size_t)HIN * WIN]     * (PRE2 / 0.15f);
        float fb = img[ib + 2 * (size_t)HIN * WIN] * (PRE2 / 0.15f);
        half_t h0 = (half_t)fx, h1 = (half_t)fy, h2 = (half_t)fr,
               h3 = (half_t)fg, h4 = (half_t)fb;
        half8 fh = {h0, h1, h2, h3, h4, (half_t)0, (half_t)0, (half_t)0};
        *(half8*)(featH + (size_t)pl * FEATW) = fh;
        float a0 = (float)h0, a1 = (float)h1, a2 = (float)h2,
              a3 = (float)h3, a4 = (float)h4;
        sqF[pl] = 0.5f * (a0 * a0 + a1 * a1 + a2 * a2 + a3 * a3 + a4 * a4);
    } else if (q == 25) {
        if (pl < NSLOT) slots[pl * 16] = 0.0f;    // one slot per cacheline
    }
}

// ---------------------------------------------------------------------------
// Main: per 16x16 pair tile, two mfma_f32_16x16x32_f16:
//   E  = mfma(afeat, bfeat, c4)   with c4[r] = -h_i(row r) - h_j(col)
//   Gs = mfma(aseg,  bseg,  0)
//   term = exp2(E) * Gs     (diag blocks add {+1,0,-inf} in log2 space)
//
// R1/R2 POST-MORTEM (hard-won):
//  * This kernel is LATENCY-bound (VALU issue floor ~7us). 64-row blocks x
//    2176 grid at launch_bounds(256,8) full residency is the proven optimum;
//    a 128-row/1088-block variant regressed 3x (residency halved).
//  * NO device-scope fences/acq-rel atomics in the epilogue: a ticket-fused
//    final reduction cost ~30ns/block in L2 wbl2/inv cache ops that evicted
//    the staged segH/featH lines for in-flight blocks (42us @1088 blocks,
//    74us @2176 blocks). Partials go to spread slots via plain (relaxed)
//    atomicAdd only; a separate 1-wave crf_final dispatch does the last sum.
//  * hJ is preloaded to 16 regs before the fully-unrolled j-loop so the only
//    per-iteration LDS traffic is the two b128 fragment reads.
// ---------------------------------------------------------------------------
__global__ __launch_bounds__(BLOCK, 8) void crf_main(const half_t* __restrict__ segH,
                                                     const half_t* __restrict__ featH,
                                                     const float* __restrict__ sqF,
                                                     float* __restrict__ slots) {
    const int bx = blockIdx.x;
    const int n  = blockIdx.y;

    // triangular decode: g = I>>2 group; 4 I's per group, 16-g J's each
    int g = 0;
#pragma unroll
    for (int t = 1; t < 16; ++t) {
        int off = 64 * t - 2 * t * (t - 1);
        if (bx >= off) g = t;
    }
    int rem = bx - (64 * g - 2 * g * (g - 1));
    int c   = 16 - g;
    int iq  = (rem >= c) + (rem >= 2 * c) + (rem >= 3 * c);
    int I   = 4 * g + iq;
    int J   = g + (rem - iq * c);
    const bool diag = (J == (I >> 2));

    const half_t* segN  = segH  + (size_t)n * PPX * SEGW;
    const half_t* featN = featH + (size_t)n * PPX * FEATW;
    const float*  sqN   = sqF   + (size_t)n * PPX;

    __shared__ alignas(16) half_t segJ[JCHUNK * SEGW];    // 12 KB
    __shared__ alignas(16) half_t featJ[JCHUNK * FEATW];  // 4 KB
    __shared__ alignas(16) half_t zrow[8];                // 16 B of zeros
    __shared__ float hJ[JCHUNK];                          // 1 KB
    __shared__ float wsum[BLOCK / 64];

    const int tid  = threadIdx.x;
    const int lane = tid & 63, wv = tid >> 6;
    const int m = lane & 15, quad = lane >> 4;
    const int i0 = I * IBLK + wv * 16;
    const int j0 = J * JCHUNK;
    const int kq = (quad < 2) ? quad : 2;   // seg k-slice (quad3 -> zero row)

    half8 hz = {};

    // A-frags from global (reused over all 16 j-tiles)
    half8 aseg  = *(const half8*)(segN  + (size_t)(i0 + m) * SEGW + kq * 8);
    half8 afeat = *(const half8*)(featN + (size_t)(i0 + m) * FEATW);
    f32x4v hi   = *(const f32x4v*)(sqN + i0 + quad * 4);  // rows quad*4..+3
    if (quad == 3) aseg  = hz;
    if (quad != 0) afeat = hz;
    f32x4v nh = -hi;

    // stage j-chunk (flat coalesced 16B copies) + zero row
    {
        const f32x4v* gsrc = (const f32x4v*)(segN + (size_t)j0 * SEGW);
        f32x4v* ldst = (f32x4v*)segJ;
#pragma unroll
        for (int v = 0; v < 3; ++v) ldst[tid + v * BLOCK] = gsrc[tid + v * BLOCK];
        ((f32x4v*)featJ)[tid] = ((const f32x4v*)(featN + (size_t)j0 * FEATW))[tid];
        hJ[tid] = sqN[j0 + tid];
        if (tid < 8) zrow[tid] = (half_t)0;
    }
    __syncthreads();

    // per-lane B pointers: stride over j-tiles, or pinned to the zero row
    const half_t* bsp; int bstep;
    if (quad == 3) { bsp = zrow;                       bstep = 0; }
    else           { bsp = segJ + m * SEGW + quad * 8; bstep = 16 * SEGW; }
    const half_t* bfp; int fstep;
    if (quad == 0) { bfp = featJ + m * FEATW;          fstep = 16 * FEATW; }
    else           { bfp = zrow;                       fstep = 0; }

    // preload the 16 per-thread h_j values (stride-16 LDS scalars) into regs
    // so the j-loop's only LDS traffic is the two b128 fragment reads.
    float hcv[16];
#pragma unroll
    for (int jt = 0; jt < 16; ++jt) hcv[jt] = hJ[jt * 16 + m];

    float racc = 0.0f;
    const f32x4v zero4 = {0.0f, 0.0f, 0.0f, 0.0f};

#pragma unroll
    for (int jt = 0; jt < JCHUNK / 16; ++jt) {   // fully unrolled: hcv static
        half8 bseg = *(const half8*)(bsp + jt * bstep);
        half8 bft  = *(const half8*)(bfp + jt * fstep);
        float hc = hcv[jt];

        f32x4v c4 = {nh[0] - hc, nh[1] - hc, nh[2] - hc, nh[3] - hc};
        f32x4v E  = __builtin_amdgcn_mfma_f32_16x16x32_f16(afeat, bft, c4, 0, 0, 0);
        f32x4v Gs = __builtin_amdgcn_mfma_f32_16x16x32_f16(aseg, bseg, zero4, 0, 0, 0);

        if (!diag) {
#pragma unroll
            for (int r = 0; r < 4; ++r)
                racc = fmaf(__builtin_amdgcn_exp2f(E[r]), Gs[r], racc);
        } else {
            const int jg = j0 + jt * 16 + m;
#pragma unroll
            for (int r = 0; r < 4; ++r) {
                int ig = i0 + quad * 4 + r;
                float sel = (jg > ig) ? 1.0f : ((jg == ig) ? 0.0f : -100000.0f);
                racc = fmaf(__builtin_amdgcn_exp2f(E[r] + sel), Gs[r], racc);
            }
        }
    }

    // reduce: thread -> wave -> block -> spread atomic slot (relaxed, no fence)
#pragma unroll
    for (int off = 32; off > 0; off >>= 1) racc += __shfl_down(racc, off);
    if (lane == 0) wsum[wv] = racc;
    __syncthreads();
    if (tid == 0) {
        float s = wsum[0] + wsum[1] + wsum[2] + wsum[3];
        if (!diag) s *= 2.0f;              // strictly-upper counts (i,j)+(j,i)
        int slot = (bx + 544 * n) & (NSLOT - 1);
        atomicAdd(&slots[slot * 16], s);
    }
}

// ---------------------------------------------------------------------------
// Final: one wave sums the 64 slots and writes the scalar output.
// (Separate dispatch on purpose — see crf_main header note on fences.)
// ---------------------------------------------------------------------------
__global__ __launch_bounds__(64) void crf_final(const float* __restrict__ slots,
                                                float* __restrict__ out) {
    int lane = threadIdx.x;
    float v = slots[lane * 16];
#pragma unroll
    for (int off = 32; off > 0; off >>= 1) v += __shfl_down(v, off);
    if (lane == 0) out[0] = v * (-5.0e-10f);   // WEIGHT * (-sum/NIMG)
}

extern "C" void kernel_launch(void* const* d_in, const int* in_sizes, int n_in,
                              void* d_out, int out_size, void* d_ws, size_t ws_size,
                              hipStream_t stream) {
    const float* img = (const float*)d_in[0];
    const float* seg = (const float*)d_in[1];
    const float* roi = (const float*)d_in[2];
    float* out = (float*)d_out;

    char* wsb = (char*)d_ws;                    // ~1.07 MB of ws used
    half_t* segH  = (half_t*)(wsb);
    half_t* featH = (half_t*)(wsb + FEATH_OFF);
    float*  sqF   = (float*)(wsb + SQF_OFF);
    float*  slots = (float*)(wsb + SLOT_OFF);

    crf_prep<<<(NPIX * 26) / BLOCK, BLOCK, 0, stream>>>(img, seg, roi,
                                                        segH, featH, sqF, slots);

    dim3 grid(544, NIMG);                       // sum_g 4*(16-g) = 544 per image
    crf_main<<<grid, BLOCK, 0, stream>>>(segH, featH, sqF, slots);

    crf_final<<<1, 64, 0, stream>>>(slots, out);
}

// Round 4
// 74.441 us; speedup vs baseline: 1.7760x; 1.0172x over previous
//
#include <hip/hip_runtime.h>

// Problem constants
#define NIMG 4
#define CCH  3
#define KCH  21
#define HIN  128
#define WIN  128
#define OH   64
#define OW   64
#define PPX  (OH*OW)          // 4096 pixels after 0.5x downsample
#define NPIX (NIMG*PPX)       // 16384 = 2^14

// feature prescale: sqrt(2)*sqrt(0.5*log2(e)) so that
//   exp(-0.5*d2) == exp2( v_i . v_j - h_i - h_j ),  h = 0.5*|v|^2
#define PRE2 1.20112241f

#define SEGW  24              // halfs per pixel: 21 seg + 3 zero (48B)
#define FEATW 8               // halfs per pixel: 5 feat + 3 zero (16B)

#define BLOCK  256
#define JCHUNK 256            // j-pixels staged per block
#define IBLK   64             // i-pixels per block

#define NSLOT  64             // partial-sum cachelines (atomic spreading)

typedef _Float16 half_t;
typedef half_t half8  __attribute__((ext_vector_type(8)));
typedef float  f32x4v __attribute__((ext_vector_type(4)));

// ws layout (bytes): segH | featH | sqF | slots
#define FEATH_OFF ((size_t)NPIX*SEGW*2)
#define SQF_OFF   (FEATH_OFF + (size_t)NPIX*FEATW*2)
#define SLOT_OFF  (SQF_OFF + (size_t)NPIX*4)

// ---------------------------------------------------------------------------
// Prep: pixel-fast indexing (g = q*NPIX + pl) so every global read is a
// 64-lane contiguous segment and featH/sqF writes coalesce.
// q<24 -> seg channel (2x2 avg pool * nearest ROI) as f16;
// q==24 -> 5 prescaled features as f16 (padded half8) + fp32 h = 0.5|v|^2
// from the f16-ROUNDED v so E_ii == 0 exactly.
// q==25, pl<64 -> zero the partial-sum slots.  Grid: q<26 (1664 blocks).
// ---------------------------------------------------------------------------
__global__ __launch_bounds__(BLOCK) void crf_prep(const float* __restrict__ img,
                                                  const float* __restrict__ seg,
                                                  const float* __restrict__ roi,
                                                  half_t* __restrict__ segH,
                                                  half_t* __restrict__ featH,
                                                  float* __restrict__ sqF,
                                                  float* __restrict__ slots) {
    int g  = blockIdx.x * BLOCK + threadIdx.x;    // [0, 26*NPIX)
    int q  = g >> 14;                             // slow: record element
    int pl = g & (NPIX - 1);                      // fast: linear pixel
    int n  = pl >> 12;
    int p  = pl & (PPX - 1);
    int y = p >> 6, x = p & 63;
    int y2 = 2 * y, x2 = 2 * x;

    if (q < SEGW) {
        float v = 0.0f;
        if (q < KCH) {
            const float* s0 = seg + (((size_t)n * KCH + q) * HIN + y2) * WIN + x2;
            float r = roi[((size_t)n * HIN + y2) * WIN + x2];
            v = 0.25f * (s0[0] + s0[1] + s0[WIN] + s0[WIN + 1]) * r;
        }
        segH[(size_t)pl * SEGW + q] = (half_t)v;
    } else if (q == 24) {
        float fx = (float)x * (PRE2 / 50.0f);
        float fy = (float)y * (PRE2 / 50.0f);
        const size_t ib = (((size_t)n * CCH) * HIN + y2) * WIN + x2;
        float fr = img[ib]                         * (PRE2 / 0.15f);
        float fg = img[ib + (size_t)HIN * WIN]     * (PRE2 / 0.15f);
        float fb = img[ib + 2 * (size_t)HIN * WIN] * (PRE2 / 0.15f);
        half_t h0 = (half_t)fx, h1 = (half_t)fy, h2 = (half_t)fr,
               h3 = (half_t)fg, h4 = (half_t)fb;
        half8 fh = {h0, h1, h2, h3, h4, (half_t)0, (half_t)0, (half_t)0};
        *(half8*)(featH + (size_t)pl * FEATW) = fh;
        float a0 = (float)h0, a1 = (float)h1, a2 = (float)h2,
              a3 = (float)h3, a4 = (float)h4;
        sqF[pl] = 0.5f * (a0 * a0 + a1 * a1 + a2 * a2 + a3 * a3 + a4 * a4);
    } else if (q == 25) {
        if (pl < NSLOT) slots[pl * 16] = 0.0f;    // one slot per cacheline
    }
}

// ---------------------------------------------------------------------------
// Main: per 16x16 pair tile, two mfma_f32_16x16x32_f16:
//   E  = mfma(afeat, bfeat, c4)   with c4[r] = -h_i(row r) - h_j(col)
//   Gs = mfma(aseg,  bseg,  0)
//   term = exp2(E) * Gs     (diag tiles add {+1,0,-inf} in log2 space)
//
// SESSION LEDGER (hard-won):
//  * LATENCY-bound kernel. 64x256 tiles, 2176 blocks, launch_bounds(256,8)
//    full residency is proven; 128-row/1088-block variant regressed 3x.
//  * NO device-scope fences/acq-rel atomics in the epilogue (ticket-fused
//    reduction cost ~30ns/block in L2 wb/inv evictions of staged data:
//    42us@1088, 74us@2176). Relaxed atomicAdd to spread slots + separate
//    1-wave crf_final only.
//  * R4: waves re-partitioned (i-half, j-half): each wave owns 2 i-sets x
//    8 jt, so each B-fragment is read by 2 waves not 4 -> per-block LDS
//    b128 reads 128->64 (the dominant non-VALU pipe cost, ~5.4us/CU).
//    MFMA/exp2 per wave unchanged; VGPR ~55 fits 8 waves/SIMD. Diag blocks
//    wave-uniformly skip fully-below-diagonal tiles (was: compute+discard).
// ---------------------------------------------------------------------------
__global__ __launch_bounds__(BLOCK, 8) void crf_main(const half_t* __restrict__ segH,
                                                     const half_t* __restrict__ featH,
                                                     const float* __restrict__ sqF,
                                                     float* __restrict__ slots) {
    const int bx = blockIdx.x;
    const int n  = blockIdx.y;

    // triangular decode: g = I>>2 group; 4 I's per group, 16-g J's each
    int g = 0;
#pragma unroll
    for (int t = 1; t < 16; ++t) {
        int off = 64 * t - 2 * t * (t - 1);
        if (bx >= off) g = t;
    }
    int rem = bx - (64 * g - 2 * g * (g - 1));
    int c   = 16 - g;
    int iq  = (rem >= c) + (rem >= 2 * c) + (rem >= 3 * c);
    int I   = 4 * g + iq;
    int J   = g + (rem - iq * c);
    const bool diag = (J == (I >> 2));

    const half_t* segN  = segH  + (size_t)n * PPX * SEGW;
    const half_t* featN = featH + (size_t)n * PPX * FEATW;
    const float*  sqN   = sqF   + (size_t)n * PPX;

    __shared__ alignas(16) half_t segJ[JCHUNK * SEGW];    // 12 KB
    __shared__ alignas(16) half_t featJ[JCHUNK * FEATW];  // 4 KB
    __shared__ alignas(16) half_t zrow[8];                // 16 B of zeros
    __shared__ float hJ[JCHUNK];                          // 1 KB
    __shared__ float wsum[BLOCK / 64];

    const int tid  = threadIdx.x;
    const int lane = tid & 63, wv = tid >> 6;
    const int m = lane & 15, quad = lane >> 4;
    const int ih  = wv >> 1;                 // i-half of the 64 rows
    const int jt0 = (wv & 1) * 8;            // first of this wave's 8 j-tiles
    const int ib0 = I * 4 + ih * 2;          // global 16-row tile indices
    const int ib1 = ib0 + 1;
    const int i00 = ib0 << 4;                // first row of set 0
    const int i01 = i00 + 16;                // first row of set 1
    const int Jt  = J << 4;                  // global 16-col tile base
    const int kq  = (quad < 2) ? quad : 2;   // seg k-slice (quad3 -> zero row)

    half8 hz = {};

    // A-frags from global: two 16-row sets per wave
    half8 aseg0  = *(const half8*)(segN  + (size_t)(i00 + m) * SEGW + kq * 8);
    half8 aseg1  = *(const half8*)(segN  + (size_t)(i01 + m) * SEGW + kq * 8);
    half8 afeat0 = *(const half8*)(featN + (size_t)(i00 + m) * FEATW);
    half8 afeat1 = *(const half8*)(featN + (size_t)(i01 + m) * FEATW);
    f32x4v hi0   = *(const f32x4v*)(sqN + i00 + quad * 4);
    f32x4v hi1   = *(const f32x4v*)(sqN + i01 + quad * 4);
    if (quad == 3) { aseg0 = hz; aseg1 = hz; }
    if (quad != 0) { afeat0 = hz; afeat1 = hz; }
    f32x4v nh0 = -hi0, nh1 = -hi1;

    // stage j-chunk (flat coalesced 16B copies) + zero row
    {
        const f32x4v* gsrc = (const f32x4v*)(segN + (size_t)((size_t)Jt << 4) * SEGW);
        f32x4v* ldst = (f32x4v*)segJ;
#pragma unroll
        for (int v = 0; v < 3; ++v) ldst[tid + v * BLOCK] = gsrc[tid + v * BLOCK];
        ((f32x4v*)featJ)[tid] = ((const f32x4v*)(featN + (size_t)((size_t)Jt << 4) * FEATW))[tid];
        hJ[tid] = sqN[(Jt << 4) + tid];
        if (tid < 8) zrow[tid] = (half_t)0;
    }
    __syncthreads();

    // per-lane B pointers over this wave's 8 j-tiles (or pinned to zero row)
    const half_t* bsp; int bstep;
    if (quad == 3) { bsp = zrow;                                    bstep = 0; }
    else           { bsp = segJ + (jt0 * 16 + m) * SEGW + quad * 8; bstep = 16 * SEGW; }
    const half_t* bfp; int fstep;
    if (quad == 0) { bfp = featJ + (jt0 * 16 + m) * FEATW;          fstep = 16 * FEATW; }
    else           { bfp = zrow;                                    fstep = 0; }

    // preload this wave's 8 h_j values into regs
    float hcv[8];
#pragma unroll
    for (int t = 0; t < 8; ++t) hcv[t] = hJ[(jt0 + t) * 16 + m];

    float racc0 = 0.0f, racc1 = 0.0f;        // independent chains per i-set
    const f32x4v zero4 = {0.0f, 0.0f, 0.0f, 0.0f};

#pragma unroll
    for (int t = 0; t < 8; ++t) {
        half8 bseg = *(const half8*)(bsp + t * bstep);
        half8 bft  = *(const half8*)(bfp + t * fstep);
        const float hc = hcv[t];
        const int jb = Jt + jt0 + t;         // global 16-col tile index
        const int jg = (jb << 4) + m;        // global j column

        // ---- i-set 0 ----
        if (!diag || jb >= ib0) {            // skip fully-below-diagonal tiles
            f32x4v c4 = {nh0[0] - hc, nh0[1] - hc, nh0[2] - hc, nh0[3] - hc};
            f32x4v E  = __builtin_amdgcn_mfma_f32_16x16x32_f16(afeat0, bft, c4, 0, 0, 0);
            f32x4v Gs = __builtin_amdgcn_mfma_f32_16x16x32_f16(aseg0, bseg, zero4, 0, 0, 0);
            if (!diag) {
#pragma unroll
                for (int r = 0; r < 4; ++r)
                    racc0 = fmaf(__builtin_amdgcn_exp2f(E[r]), Gs[r], racc0);
            } else if (jb > ib0) {           // fully above: x2 via +1 in log2
#pragma unroll
                for (int r = 0; r < 4; ++r)
                    racc0 = fmaf(__builtin_amdgcn_exp2f(E[r] + 1.0f), Gs[r], racc0);
            } else {                         // straddles the diagonal
#pragma unroll
                for (int r = 0; r < 4; ++r) {
                    int ig = i00 + quad * 4 + r;
                    float sel = (jg > ig) ? 1.0f : ((jg == ig) ? 0.0f : -100000.0f);
                    racc0 = fmaf(__builtin_amdgcn_exp2f(E[r] + sel), Gs[r], racc0);
                }
            }
        }

        // ---- i-set 1 ----
        if (!diag || jb >= ib1) {
            f32x4v c4 = {nh1[0] - hc, nh1[1] - hc, nh1[2] - hc, nh1[3] - hc};
            f32x4v E  = __builtin_amdgcn_mfma_f32_16x16x32_f16(afeat1, bft, c4, 0, 0, 0);
            f32x4v Gs = __builtin_amdgcn_mfma_f32_16x16x32_f16(aseg1, bseg, zero4, 0, 0, 0);
            if (!diag) {
#pragma unroll
                for (int r = 0; r < 4; ++r)
                    racc1 = fmaf(__builtin_amdgcn_exp2f(E[r]), Gs[r], racc1);
            } else if (jb > ib1) {
#pragma unroll
                for (int r = 0; r < 4; ++r)
                    racc1 = fmaf(__builtin_amdgcn_exp2f(E[r] + 1.0f), Gs[r], racc1);
            } else {
#pragma unroll
                for (int r = 0; r < 4; ++r) {
                    int ig = i01 + quad * 4 + r;
                    float sel = (jg > ig) ? 1.0f : ((jg == ig) ? 0.0f : -100000.0f);
                    racc1 = fmaf(__builtin_amdgcn_exp2f(E[r] + sel), Gs[r], racc1);
                }
            }
        }
    }

    // reduce: thread -> wave -> block -> spread atomic slot (relaxed, no fence)
    float racc = racc0 + racc1;
#pragma unroll
    for (int off = 32; off > 0; off >>= 1) racc += __shfl_down(racc, off);
    if (lane == 0) wsum[wv] = racc;
    __syncthreads();
    if (tid == 0) {
        float s = wsum[0] + wsum[1] + wsum[2] + wsum[3];
        if (!diag) s *= 2.0f;              // strictly-upper counts (i,j)+(j,i)
        int slot = (bx + 544 * n) & (NSLOT - 1);
        atomicAdd(&slots[slot * 16], s);
    }
}

// ---------------------------------------------------------------------------
// Final: one wave sums the 64 slots and writes the scalar output.
// (Separate dispatch on purpose — see crf_main header note on fences.)
// ---------------------------------------------------------------------------
__global__ __launch_bounds__(64) void crf_final(const float* __restrict__ slots,
                                                float* __restrict__ out) {
    int lane = threadIdx.x;
    float v = slots[lane * 16];
#pragma unroll
    for (int off = 32; off > 0; off >>= 1) v += __shfl_down(v, off);
    if (lane == 0) out[0] = v * (-5.0e-10f);   // WEIGHT * (-sum/NIMG)
}

extern "C" void kernel_launch(void* const* d_in, const int* in_sizes, int n_in,
                              void* d_out, int out_size, void* d_ws, size_t ws_size,
                              hipStream_t stream) {
    const float* img = (const float*)d_in[0];
    const float* seg = (const float*)d_in[1];
    const float* roi = (const float*)d_in[2];
    float* out = (float*)d_out;

    char* wsb = (char*)d_ws;                    // ~1.07 MB of ws used
    half_t* segH  = (half_t*)(wsb);
    half_t* featH = (half_t*)(wsb + FEATH_OFF);
    float*  sqF   = (float*)(wsb + SQF_OFF);
    float*  slots = (float*)(wsb + SLOT_OFF);

    crf_prep<<<(NPIX * 26) / BLOCK, BLOCK, 0, stream>>>(img, seg, roi,
                                                        segH, featH, sqF, slots);

    dim3 grid(544, NIMG);                       // sum_g 4*(16-g) = 544 per image
    crf_main<<<grid, BLOCK, 0, stream>>>(segH, featH, sqF, slots);

    crf_final<<<1, 64, 0, stream>>>(slots, out);
}